// Round 13
// baseline (1022.868 us; speedup 1.0000x reference)
//
#include <hip/hip_runtime.h>
#include <hip/hip_fp16.h>

#define NN 50000
#define NE 800000
#define NG 256
#define BN_EPS 1e-5f
#define NNP (196 * 256)   // padded bins for scan

typedef __attribute__((ext_vector_type(8))) _Float16 half8v;
typedef __attribute__((ext_vector_type(4))) _Float16 half4v;
typedef __attribute__((ext_vector_type(4))) float f32x4;

__device__ __forceinline__ float sigm(float x) { return 1.0f / (1.0f + __expf(-x)); }
__device__ __forceinline__ float sofp(float x) { return fmaxf(x, 0.0f) + __logf(1.0f + __expf(-fabsf(x))); }

// ================= CSR build (counting sort by dst) =================
__global__ __launch_bounds__(256) void k_hist(const int* __restrict__ ei, int* __restrict__ hist)
{
    const int e = blockIdx.x * 256 + threadIdx.x;
    if (e < NE) atomicAdd(&hist[ei[NE + e]], 1);
}

__global__ __launch_bounds__(256) void k_scan_partial(const int* __restrict__ hist, int* __restrict__ partial)
{
    __shared__ int s[256];
    const int t = threadIdx.x;
    s[t] = hist[blockIdx.x * 256 + t];
    __syncthreads();
    for (int off = 1; off < 256; off <<= 1) {
        const int u = (t >= off) ? s[t - off] : 0;
        __syncthreads();
        s[t] += u;
        __syncthreads();
    }
    if (t == 255) partial[blockIdx.x] = s[255];
}

__global__ __launch_bounds__(256) void k_scan_top(const int* __restrict__ partial, int* __restrict__ topoff)
{
    __shared__ int s[256];
    const int t = threadIdx.x;
    const int v = (t < 196) ? partial[t] : 0;
    s[t] = v;
    __syncthreads();
    for (int off = 1; off < 256; off <<= 1) {
        const int u = (t >= off) ? s[t - off] : 0;
        __syncthreads();
        s[t] += u;
        __syncthreads();
    }
    if (t < 196) topoff[t] = s[t] - v;  // exclusive
}

__global__ __launch_bounds__(256) void k_scan_final(const int* __restrict__ hist, const int* __restrict__ topoff,
                                                    int* __restrict__ cursor)
{
    __shared__ int s[256];
    const int t = threadIdx.x;
    const int i = blockIdx.x * 256 + t;
    const int v = hist[i];
    s[t] = v;
    __syncthreads();
    for (int off = 1; off < 256; off <<= 1) {
        const int u = (t >= off) ? s[t - off] : 0;
        __syncthreads();
        s[t] += u;
        __syncthreads();
    }
    if (i < NN) cursor[i] = topoff[blockIdx.x] + s[t] - v;  // exclusive prefix
}

__global__ __launch_bounds__(256) void k_scatter(const int* __restrict__ ei, int* __restrict__ cursor,
                                                 int* __restrict__ seid, int* __restrict__ epos,
                                                 int2* __restrict__ sds)
{
    const int e = blockIdx.x * 256 + threadIdx.x;
    if (e < NE) {
        const int d = ei[NE + e];
        const int pos = atomicAdd(&cursor[d], 1);
        seid[pos] = e;
        epos[e] = pos;
        sds[pos] = make_int2(ei[e], d);
    }
}

// permute edge_attr into sorted order, fp16: SEQUENTIAL read, scattered 128B write
__global__ __launch_bounds__(256) void k_eperm2(const int* __restrict__ epos, const float* __restrict__ ea,
                                                _Float16* __restrict__ eas)
{
    const int e = blockIdx.x * 16 + (threadIdx.x >> 4);
    const int j = threadIdx.x & 15;
    const int p = epos[e];
    const float4 v = *(const float4*)(ea + (size_t)e * 64 + j * 4);
    half4v h;
    h[0] = (_Float16)v.x; h[1] = (_Float16)v.y; h[2] = (_Float16)v.z; h[3] = (_Float16)v.w;
    *(half4v*)(eas + (size_t)p * 64 + j * 4) = h;
}

// ================= one-time W conversion to fp16 pre-swizzled images =================
__global__ __launch_bounds__(256) void k_wcvt(
    const float* __restrict__ Wf0, const float* __restrict__ Ws0,
    const float* __restrict__ Wf1, const float* __restrict__ Ws1,
    unsigned short* __restrict__ Wn16, unsigned short* __restrict__ We16)
{
    const int i = blockIdx.x * 256 + threadIdx.x;
    if (i >= 2 * 81920) return;
    const int l = i / 81920;
    int r = i % 81920;
    const float* Wf = l ? Wf1 : Wf0;
    const float* Ws = l ? Ws1 : Ws0;
    if (r < 65536) {
        const int s = r >> 14;          // 0..3
        const int t = s & 1, g = s >> 1;
        const int j = r & 16383;
        const int k = j >> 7, ch = j & 127;
        const float v = (g ? Ws : Wf)[(size_t)(t * 128 + k) * 128 + ch];
        unsigned short* img = Wn16 + (size_t)(l * 2 + t) * 32768;
        const int boff = g * 32768 + ch * 256 + ((k * 2) ^ ((ch & 7) << 4));
        *(unsigned short*)((char*)img + boff) = __half_as_ushort(__float2half(v));
    } else {
        r -= 65536;
        const int g = r >> 13;
        const int j = r & 8191;
        const int k = j >> 7, ch = j & 127;
        const float v = (g ? Ws : Wf)[(size_t)(256 + k) * 128 + ch];
        const int row = g * 128 + ch;
        unsigned short* img = We16 + (size_t)l * 16384;
        const int boff = row * 128 + ((k * 2) ^ ((row & 7) << 4));
        *(unsigned short*)((char*)img + boff) = __half_as_ushort(__float2half(v));
    }
}

// ================= node linear (MFMA f16, single-term, packed fp16 tables) =================
// blockIdx.y = t: 0 -> Tdw (+bias), 1 -> Tsw. BN=1: normalize xin on load with a,b from stats.
template<int BN>
__global__ __launch_bounds__(256) void k_nl(
    const float* __restrict__ xin, const unsigned short* __restrict__ Wimg,
    const float* __restrict__ bfv, const float* __restrict__ bsv,
    const float* __restrict__ stats, const float* __restrict__ gmv, const float* __restrict__ bev,
    unsigned int* __restrict__ Tdw, unsigned int* __restrict__ Tsw)
{
    const int t = blockIdx.y;
    __shared__ short Wg[32768];   // 64 KB: gate f at 0, gate s at +32768 B
    __shared__ float abv[256];
    const int tid = threadIdx.x;
    {
        const int4* src = (const int4*)(Wimg + (size_t)t * 32768);
        int4* dst = (int4*)Wg;
        for (int j = tid; j < 4096; j += 256) dst[j] = src[j];
    }
    if (BN && tid < 128) {
        const float mu = stats[tid] * (1.0f / NN);
        const float var = stats[128 + tid] * (1.0f / NN) - mu * mu;
        const float a = gmv[tid] * rsqrtf(var + BN_EPS);
        abv[tid] = a;
        abv[128 + tid] = fmaf(-mu, a, bev[tid]);
    }
    __syncthreads();

    const int lane = tid & 63;
    const int ln = lane & 15, lg = lane >> 4, wv = tid >> 6;
    const int nb = blockIdx.x * 64 + wv * 16;
    const int arow = (nb + ln < NN) ? nb + ln : NN - 1;
    const int sw = (ln & 7) << 4;

    f32x4 accF[8], accS[8];
    const f32x4 zz = {0.f, 0.f, 0.f, 0.f};
#pragma unroll
    for (int nt = 0; nt < 8; ++nt) { accF[nt] = zz; accS[nt] = zz; }

    const char* wg = (const char*)Wg;
    for (int kc = 0; kc < 4; ++kc) {
        const float* ap = xin + (size_t)arow * 128 + kc * 32 + lg * 8;
        const float4 u0 = *(const float4*)(ap);
        const float4 u1 = *(const float4*)(ap + 4);
        float av[8] = {u0.x, u0.y, u0.z, u0.w, u1.x, u1.y, u1.z, u1.w};
        half8v xh;
#pragma unroll
        for (int i = 0; i < 8; ++i) {
            if (BN) {
                const int ch = kc * 32 + lg * 8 + i;
                av[i] = fmaf(av[i], abv[ch], abv[128 + ch]);
            }
            xh[i] = (_Float16)av[i];
        }
        const int kofs = (kc * 64 + lg * 16) ^ sw;
#pragma unroll
        for (int nt = 0; nt < 8; ++nt) {
            const int row = nt * 16 + ln;
            const half8v bF = *(const half8v*)(wg + row * 256 + kofs);
            const half8v bS = *(const half8v*)(wg + 32768 + row * 256 + kofs);
            accF[nt] = __builtin_amdgcn_mfma_f32_16x16x32_f16(xh, bF, accF[nt], 0, 0, 0);
            accS[nt] = __builtin_amdgcn_mfma_f32_16x16x32_f16(xh, bS, accS[nt], 0, 0, 0);
        }
    }

    unsigned int* Tw = t ? Tsw : Tdw;
#pragma unroll
    for (int nt = 0; nt < 8; ++nt) {
        const int ch = nt * 16 + ln;
        float addF = 0.f, addS = 0.f;
        if (t == 0) { addF = bfv[ch]; addS = bsv[ch]; }
#pragma unroll
        for (int r = 0; r < 4; ++r) {
            const int node = nb + lg * 4 + r;
            if (node < NN) {
                const __half2 p = __floats2half2_rn(accF[nt][r] + addF, accS[nt][r] + addS);
                Tw[(size_t)node * 128 + ch] = *(const unsigned int*)&p;
            }
        }
    }
}

// ===== fused edge kernel: wave-pair channel split + software-pipelined index/ea prefetch =====
// Wave pair (2w,2w+1) shares one edge range; h = gw&1 selects channels h*64..h*64+63.
template<int PERM>
__global__ __launch_bounds__(256, 4) void k_edge8(
    const unsigned int* __restrict__ Tdw, const unsigned int* __restrict__ Tsw,
    const unsigned short* __restrict__ Wimg,
    const int* __restrict__ seid, const int2* __restrict__ sds,
    const float* __restrict__ ea, const _Float16* __restrict__ eas,
    float* __restrict__ agg)
{
    __shared__ short Wt[16384];   // 32 KB edge-slice image
    const int tid = threadIdx.x;
    {
        const int4* src = (const int4*)Wimg;
        int4* dst = (int4*)Wt;
        for (int j = tid; j < 2048; j += 256) dst[j] = src[j];
    }
    __syncthreads();

    const int lane = tid & 63;
    const int ln = lane & 15, lg = lane >> 4;
    const int gw = blockIdx.x * 4 + (tid >> 6);
    const int h = gw & 1;                 // channel half
    const int rid = gw >> 1;              // edge-range id
    const int nrng = (gridDim.x * 4) >> 1;
    const int sw = (ln & 7) << 4;
    const int co = h * 64;                // channel offset

    const int NCH = NE / 16;
    const int lo = (int)(((long long)rid * NCH) / nrng);
    const int hi = (int)(((long long)(rid + 1) * NCH) / nrng);
    if (lo >= hi) return;
    const int wlo = lo * 16;
    const int Q = (hi - lo) * 4;       // edges per lane-group (contiguous)
    const int NT = hi - lo;

    const int abase = wlo + (ln >> 2) * Q + (ln & 3);  // A-row edge (+ t*4)
    const int gbase = wlo + lg * Q;                    // C-group edge base (+ t*4 + r)

    float pend[4];
    float2 gdc[4];
    int pdn = -1;
    bool first = true;
#pragma unroll
    for (int nt = 0; nt < 4; ++nt) { pend[nt] = 0.f; gdc[nt] = make_float2(0.f, 0.f); }

    const char* wb = (const char*)Wt;

    // pipeline state: current tile's indices + A fragments
    int4 p01 = *(const int4*)(sds + gbase);
    int4 p23 = *(const int4*)(sds + gbase + 2);
    half8v a0, a1;
    if (PERM) {
        const _Float16* ap = eas + (size_t)abase * 64;
        a0 = *(const half8v*)(ap + lg * 8);
        a1 = *(const half8v*)(ap + 32 + lg * 8);
    }

    for (int t = 0; t < NT; ++t) {
        // issue next-tile loads first (latency hidden under this tile's work)
        const int t1 = (t + 1 < NT) ? t + 1 : t;
        const int4 n01 = *(const int4*)(sds + gbase + t1 * 4);
        const int4 n23 = *(const int4*)(sds + gbase + t1 * 4 + 2);
        half8v na0, na1;
        if (PERM) {
            const _Float16* np = eas + (size_t)(abase + t1 * 4) * 64;
            na0 = *(const half8v*)(np + lg * 8);
            na1 = *(const half8v*)(np + 32 + lg * 8);
        } else {
            const int eln = seid[abase + t * 4];
            const float* ap = ea + (size_t)eln * 64 + lg * 8;
            const float4 v0 = *(const float4*)(ap);
            const float4 v1 = *(const float4*)(ap + 4);
            const float4 v2 = *(const float4*)(ap + 32);
            const float4 v3 = *(const float4*)(ap + 36);
            const float av0[8] = {v0.x, v0.y, v0.z, v0.w, v1.x, v1.y, v1.z, v1.w};
            const float av1[8] = {v2.x, v2.y, v2.z, v2.w, v3.x, v3.y, v3.z, v3.w};
#pragma unroll
            for (int i = 0; i < 8; ++i) { a0[i] = (_Float16)av0[i]; a1[i] = (_Float16)av1[i]; }
        }

        const int sn[4] = {p01.x, p01.z, p23.x, p23.z};
        const int dn[4] = {p01.y, p01.w, p23.y, p23.w};

        // Tsrc gathers for this channel half (addresses ready from prefetched indices)
        unsigned int gsw[4][4];
#pragma unroll
        for (int r = 0; r < 4; ++r)
#pragma unroll
            for (int nt = 0; nt < 4; ++nt)
                gsw[r][nt] = Tsw[(size_t)sn[r] * 128 + co + nt * 16 + ln];

        f32x4 accf[4], accs[4];
        const f32x4 zz = {0.f, 0.f, 0.f, 0.f};
#pragma unroll
        for (int nt = 0; nt < 4; ++nt) { accf[nt] = zz; accs[nt] = zz; }

#pragma unroll
        for (int nt = 0; nt < 4; ++nt) {
            const int rowf = co + nt * 16 + ln;
            const half8v bf0 = *(const half8v*)(wb + rowf * 128 + ((lg * 16) ^ sw));
            const half8v bf1 = *(const half8v*)(wb + rowf * 128 + ((64 + lg * 16) ^ sw));
            const half8v bs0 = *(const half8v*)(wb + (128 + rowf) * 128 + ((lg * 16) ^ sw));
            const half8v bs1 = *(const half8v*)(wb + (128 + rowf) * 128 + ((64 + lg * 16) ^ sw));
            accf[nt] = __builtin_amdgcn_mfma_f32_16x16x32_f16(a0, bf0, accf[nt], 0, 0, 0);
            accf[nt] = __builtin_amdgcn_mfma_f32_16x16x32_f16(a1, bf1, accf[nt], 0, 0, 0);
            accs[nt] = __builtin_amdgcn_mfma_f32_16x16x32_f16(a0, bs0, accs[nt], 0, 0, 0);
            accs[nt] = __builtin_amdgcn_mfma_f32_16x16x32_f16(a1, bs1, accs[nt], 0, 0, 0);
        }

        // epilogue: runs carried across tiles; interior runs = plain store
#pragma unroll
        for (int r = 0; r < 4; ++r) {
            if (dn[r] != pdn) {
                if (pdn >= 0) {
                    float* xo = agg + (size_t)pdn * 128 + co + ln;
                    if (first) {
#pragma unroll
                        for (int nt = 0; nt < 4; ++nt) atomicAdd(xo + nt * 16, pend[nt]);
                    } else {
#pragma unroll
                        for (int nt = 0; nt < 4; ++nt) xo[nt * 16] = pend[nt];
                    }
                    first = false;
                }
                pdn = dn[r];
#pragma unroll
                for (int nt = 0; nt < 4; ++nt) {
                    const __half2 hd = *(const __half2*)&Tdw[(size_t)pdn * 128 + co + nt * 16 + ln];
                    gdc[nt] = __half22float2(hd);
                    pend[nt] = 0.f;
                }
            }
#pragma unroll
            for (int nt = 0; nt < 4; ++nt) {
                const __half2 hw = *(const __half2*)&gsw[r][nt];
                const float2 gs = __half22float2(hw);
                const float F = accf[nt][r] + gdc[nt].x + gs.x;
                const float S = accs[nt][r] + gdc[nt].y + gs.y;
                pend[nt] += sigm(F) * sofp(S);
            }
        }

        // rotate pipeline state
        p01 = n01; p23 = n23;
        if (PERM) { a0 = na0; a1 = na1; }
    }
    // final run touches the range boundary: atomic
    {
        float* xo = agg + (size_t)pdn * 128 + co + ln;
#pragma unroll
        for (int nt = 0; nt < 4; ++nt) atomicAdd(xo + nt * 16, pend[nt]);
    }
}

// ================= batchnorm stats (optionally BN-on-load of xv; optionally writes v) =================
template<int WRITE, int BN>
__global__ __launch_bounds__(256) void k_bn_stats2(
    const float* __restrict__ xv, const float* __restrict__ agg,
    const float* __restrict__ pstats, const float* __restrict__ pgm, const float* __restrict__ pbe,
    float* __restrict__ vout, float* __restrict__ stats)
{
    const int c = threadIdx.x & 127;
    const int half = threadIdx.x >> 7;
    float a = 1.0f, b = 0.0f;
    if (BN) {
        const float mu = pstats[c] * (1.0f / NN);
        const float var = pstats[128 + c] * (1.0f / NN) - mu * mu;
        a = pgm[c] * rsqrtf(var + BN_EPS);
        b = fmaf(-mu, a, pbe[c]);
    }
    float s = 0.0f, q = 0.0f;
    for (int r = blockIdx.x * 2 + half; r < NN; r += gridDim.x * 2) {
        float v = xv[(size_t)r * 128 + c];
        if (BN) v = fmaf(v, a, b);
        v += agg[(size_t)r * 128 + c];
        if (WRITE) vout[(size_t)r * 128 + c] = v;
        s += v; q = fmaf(v, v, q);
    }
    __shared__ float sh[2][128];
    if (half) { sh[0][c] = s; sh[1][c] = q; }
    __syncthreads();
    if (!half) {
        s += sh[0][c]; q += sh[1][c];
        atomicAdd(&stats[c], s);
        atomicAdd(&stats[128 + c], q);
    }
}

// final: out-pool of BN1(BN0(v1)+agg1)
__global__ __launch_bounds__(256) void k_bn_apply_pool2(
    const float* __restrict__ v1, const float* __restrict__ agg,
    const float* __restrict__ stats0, const float* __restrict__ gm0, const float* __restrict__ be0,
    const float* __restrict__ stats1, const float* __restrict__ gm1, const float* __restrict__ be1,
    const int* __restrict__ bat, float* __restrict__ pool, float* __restrict__ cnt)
{
    const int c = threadIdx.x & 127;
    const int half = threadIdx.x >> 7;
    float a0, b0, a1, b1;
    {
        const float mu = stats0[c] * (1.0f / NN);
        const float var = stats0[128 + c] * (1.0f / NN) - mu * mu;
        a0 = gm0[c] * rsqrtf(var + BN_EPS);
        b0 = fmaf(-mu, a0, be0[c]);
    }
    {
        const float mu = stats1[c] * (1.0f / NN);
        const float var = stats1[128 + c] * (1.0f / NN) - mu * mu;
        a1 = gm1[c] * rsqrtf(var + BN_EPS);
        b1 = fmaf(-mu, a1, be1[c]);
    }
    for (int r = blockIdx.x * 2 + half; r < NN; r += gridDim.x * 2) {
        const int g = bat[r];
        const float v = fmaf(v1[(size_t)r * 128 + c], a0, b0) + agg[(size_t)r * 128 + c];
        atomicAdd(&pool[(size_t)g * 128 + c], fmaf(v, a1, b1));
        if (c == 0) atomicAdd(&cnt[g], 1.0f);
    }
}

__global__ __launch_bounds__(256) void k_pool_fin(const float* __restrict__ pool, const float* __restrict__ cnt,
                                                  float* __restrict__ out)
{
    const int i = blockIdx.x * 256 + threadIdx.x;
    out[i] = pool[i] / fmaxf(cnt[i >> 7], 1.0f);
}

extern "C" void kernel_launch(void* const* d_in, const int* in_sizes, int n_in,
                              void* d_out, int out_size, void* d_ws, size_t ws_size,
                              hipStream_t stream)
{
    const float* x   = (const float*)d_in[0];
    const int*   ei  = (const int*)d_in[1];
    const float* ea  = (const float*)d_in[2];
    const int*   bat = (const int*)d_in[3];
    const float* Wf[2] = { (const float*)d_in[4],  (const float*)d_in[10] };
    const float* bf[2] = { (const float*)d_in[5],  (const float*)d_in[11] };
    const float* Ws[2] = { (const float*)d_in[6],  (const float*)d_in[12] };
    const float* bs[2] = { (const float*)d_in[7],  (const float*)d_in[13] };
    const float* gm[2] = { (const float*)d_in[8],  (const float*)d_in[14] };
    const float* be[2] = { (const float*)d_in[9],  (const float*)d_in[15] };

    char* wsp = (char*)d_ws;
    unsigned int* Tdw = (unsigned int*)wsp;                 // [N][128] packed half2 (f,s)
    unsigned int* Tsw = Tdw + (size_t)NN * 128;             // [N][128] packed half2
    float* agg    = (float*)(Tsw + (size_t)NN * 128);       // [N][128] fp32
    float* xb1    = agg + (size_t)NN * 128;                 // [N][128] fp32: v1 = x + agg0 (pre-BN)
    float* stats0 = xb1 + (size_t)NN * 128;                 // 256
    float* stats1 = stats0 + 256;                           // 256
    float* pool   = stats1 + 256;                           // [G][128]
    float* cnt    = pool + (size_t)NG * 128;                // G
    int* hist    = (int*)(cnt + NG);                        // NNP
    int* partial = hist + NNP;                              // 256
    int* topoff  = partial + 256;                           // 256
    int* cursor  = topoff + 256;                            // NN
    int* seid    = cursor + NN;                             // NE
    int* epos    = seid + NE;                               // NE
    int2* sds    = (int2*)(epos + NE);                      // NE int2
    unsigned short* Wn16 = (unsigned short*)(sds + NE);     // 131072 ushorts
    unsigned short* We16 = Wn16 + 131072;                   // 32768 ushorts
    _Float16* eas = (_Float16*)(We16 + 32768);              // NE*64 halves (102.4 MB)

    const size_t need = (size_t)((char*)(eas + (size_t)NE * 64) - (char*)d_ws);
    const bool perm = ws_size >= need;

    hipMemsetAsync(pool, 0, ((size_t)NG * 128 + NG) * sizeof(float), stream);
    hipMemsetAsync(hist, 0, NNP * sizeof(int), stream);
    hipMemsetAsync(stats0, 0, 512 * sizeof(float), stream);

    // one-time: W conversion + dst-sorted edge permutation (+ ea perm/cvt)
    k_wcvt<<<640, 256, 0, stream>>>(Wf[0], Ws[0], Wf[1], Ws[1], Wn16, We16);
    k_hist<<<(NE + 255) / 256, 256, 0, stream>>>(ei, hist);
    k_scan_partial<<<196, 256, 0, stream>>>(hist, partial);
    k_scan_top<<<1, 256, 0, stream>>>(partial, topoff);
    k_scan_final<<<196, 256, 0, stream>>>(hist, topoff, cursor);
    k_scatter<<<(NE + 255) / 256, 256, 0, stream>>>(ei, cursor, seid, epos, sds);
    if (perm) k_eperm2<<<NE / 16, 256, 0, stream>>>(epos, ea, eas);

    // ---- layer 1 ----
    k_nl<0><<<dim3(782, 2), 256, 0, stream>>>(x, Wn16, bf[0], bs[0], nullptr, nullptr, nullptr, Tdw, Tsw);
    hipMemsetAsync(agg, 0, (size_t)NN * 128 * sizeof(float), stream);
    if (perm) k_edge8<1><<<1024, 256, 0, stream>>>(Tdw, Tsw, We16, seid, sds, ea, eas, agg);
    else      k_edge8<0><<<1024, 256, 0, stream>>>(Tdw, Tsw, We16, seid, sds, ea, eas, agg);
    // stats0 over v1 = x + agg0; also materialize v1 into xb1
    k_bn_stats2<1, 0><<<256, 256, 0, stream>>>(x, agg, nullptr, nullptr, nullptr, xb1, stats0);

    // ---- layer 2 ----  (BN0 folded into consumers)
    k_nl<1><<<dim3(782, 2), 256, 0, stream>>>(xb1, Wn16 + 65536, bf[1], bs[1], stats0, gm[0], be[0], Tdw, Tsw);
    hipMemsetAsync(agg, 0, (size_t)NN * 128 * sizeof(float), stream);
    hipMemsetAsync(stats1, 0, 256 * sizeof(float), stream);
    if (perm) k_edge8<1><<<1024, 256, 0, stream>>>(Tdw, Tsw, We16 + 16384, seid, sds, ea, eas, agg);
    else      k_edge8<0><<<1024, 256, 0, stream>>>(Tdw, Tsw, We16 + 16384, seid, sds, ea, eas, agg);
    k_bn_stats2<0, 1><<<256, 256, 0, stream>>>(xb1, agg, stats0, gm[0], be[0], nullptr, stats1);
    k_bn_apply_pool2<<<256, 256, 0, stream>>>(xb1, agg, stats0, gm[0], be[0], stats1, gm[1], be[1], bat, pool, cnt);

    k_pool_fin<<<NG * 128 / 256, 256, 0, stream>>>(pool, cnt, (float*)d_out);
}

// Round 14
// 969.577 us; speedup vs baseline: 1.0550x; 1.0550x over previous
//
#include <hip/hip_runtime.h>
#include <hip/hip_fp16.h>

#define NN 50000
#define NE 800000
#define NG 256
#define BN_EPS 1e-5f
#define NNP (196 * 256)   // padded bins for scan

typedef __attribute__((ext_vector_type(8))) _Float16 half8v;
typedef __attribute__((ext_vector_type(4))) _Float16 half4v;
typedef __attribute__((ext_vector_type(4))) float f32x4;

__device__ __forceinline__ float sigm(float x) { return 1.0f / (1.0f + __expf(-x)); }
__device__ __forceinline__ float sofp(float x) { return fmaxf(x, 0.0f) + __logf(1.0f + __expf(-fabsf(x))); }

// ================= CSR build (counting sort by dst) =================
__global__ __launch_bounds__(256) void k_hist(const int* __restrict__ ei, int* __restrict__ hist)
{
    const int e = blockIdx.x * 256 + threadIdx.x;
    if (e < NE) atomicAdd(&hist[ei[NE + e]], 1);
}

__global__ __launch_bounds__(256) void k_scan_partial(const int* __restrict__ hist, int* __restrict__ partial)
{
    __shared__ int s[256];
    const int t = threadIdx.x;
    s[t] = hist[blockIdx.x * 256 + t];
    __syncthreads();
    for (int off = 1; off < 256; off <<= 1) {
        const int u = (t >= off) ? s[t - off] : 0;
        __syncthreads();
        s[t] += u;
        __syncthreads();
    }
    if (t == 255) partial[blockIdx.x] = s[255];
}

__global__ __launch_bounds__(256) void k_scan_top(const int* __restrict__ partial, int* __restrict__ topoff)
{
    __shared__ int s[256];
    const int t = threadIdx.x;
    const int v = (t < 196) ? partial[t] : 0;
    s[t] = v;
    __syncthreads();
    for (int off = 1; off < 256; off <<= 1) {
        const int u = (t >= off) ? s[t - off] : 0;
        __syncthreads();
        s[t] += u;
        __syncthreads();
    }
    if (t < 196) topoff[t] = s[t] - v;  // exclusive
}

__global__ __launch_bounds__(256) void k_scan_final(const int* __restrict__ hist, const int* __restrict__ topoff,
                                                    int* __restrict__ cursor)
{
    __shared__ int s[256];
    const int t = threadIdx.x;
    const int i = blockIdx.x * 256 + t;
    const int v = hist[i];
    s[t] = v;
    __syncthreads();
    for (int off = 1; off < 256; off <<= 1) {
        const int u = (t >= off) ? s[t - off] : 0;
        __syncthreads();
        s[t] += u;
        __syncthreads();
    }
    if (i < NN) cursor[i] = topoff[blockIdx.x] + s[t] - v;  // exclusive prefix
}

__global__ __launch_bounds__(256) void k_scatter(const int* __restrict__ ei, int* __restrict__ cursor,
                                                 int* __restrict__ seid, int* __restrict__ epos,
                                                 int2* __restrict__ sds)
{
    const int e = blockIdx.x * 256 + threadIdx.x;
    if (e < NE) {
        const int d = ei[NE + e];
        const int pos = atomicAdd(&cursor[d], 1);
        seid[pos] = e;
        epos[e] = pos;
        sds[pos] = make_int2(ei[e], d);
    }
}

// permute edge_attr into sorted order, fp16: SEQUENTIAL read, scattered 128B write
__global__ __launch_bounds__(256) void k_eperm2(const int* __restrict__ epos, const float* __restrict__ ea,
                                                _Float16* __restrict__ eas)
{
    const int e = blockIdx.x * 16 + (threadIdx.x >> 4);
    const int j = threadIdx.x & 15;
    const int p = epos[e];
    const float4 v = *(const float4*)(ea + (size_t)e * 64 + j * 4);
    half4v h;
    h[0] = (_Float16)v.x; h[1] = (_Float16)v.y; h[2] = (_Float16)v.z; h[3] = (_Float16)v.w;
    *(half4v*)(eas + (size_t)p * 64 + j * 4) = h;
}

// ================= one-time W conversion to fp16 pre-swizzled images =================
__global__ __launch_bounds__(256) void k_wcvt(
    const float* __restrict__ Wf0, const float* __restrict__ Ws0,
    const float* __restrict__ Wf1, const float* __restrict__ Ws1,
    unsigned short* __restrict__ Wn16, unsigned short* __restrict__ We16)
{
    const int i = blockIdx.x * 256 + threadIdx.x;
    if (i >= 2 * 81920) return;
    const int l = i / 81920;
    int r = i % 81920;
    const float* Wf = l ? Wf1 : Wf0;
    const float* Ws = l ? Ws1 : Ws0;
    if (r < 65536) {
        const int s = r >> 14;          // 0..3
        const int t = s & 1, g = s >> 1;
        const int j = r & 16383;
        const int k = j >> 7, ch = j & 127;
        const float v = (g ? Ws : Wf)[(size_t)(t * 128 + k) * 128 + ch];
        unsigned short* img = Wn16 + (size_t)(l * 2 + t) * 32768;
        const int boff = g * 32768 + ch * 256 + ((k * 2) ^ ((ch & 7) << 4));
        *(unsigned short*)((char*)img + boff) = __half_as_ushort(__float2half(v));
    } else {
        r -= 65536;
        const int g = r >> 13;
        const int j = r & 8191;
        const int k = j >> 7, ch = j & 127;
        const float v = (g ? Ws : Wf)[(size_t)(256 + k) * 128 + ch];
        const int row = g * 128 + ch;
        unsigned short* img = We16 + (size_t)l * 16384;
        const int boff = row * 128 + ((k * 2) ^ ((row & 7) << 4));
        *(unsigned short*)((char*)img + boff) = __half_as_ushort(__float2half(v));
    }
}

// ===== node linear, fused dst+src passes: x fragments loaded ONCE, W image reloaded =====
// pass 0: Tdw (+bias) from image t=0; pass 1: Tsw from image t=1. BN=1: fold BN into x load.
template<int BN>
__global__ __launch_bounds__(256) void k_nl2(
    const float* __restrict__ xin, const unsigned short* __restrict__ Wimg,
    const float* __restrict__ bfv, const float* __restrict__ bsv,
    const float* __restrict__ stats, const float* __restrict__ gmv, const float* __restrict__ bev,
    unsigned int* __restrict__ Tdw, unsigned int* __restrict__ Tsw)
{
    __shared__ short Wg[32768];   // 64 KB: gate f at 0, gate s at +32768 B (one t-image)
    __shared__ float abv[256];
    const int tid = threadIdx.x;
    {
        const int4* src = (const int4*)Wimg;
        int4* dst = (int4*)Wg;
        for (int j = tid; j < 4096; j += 256) dst[j] = src[j];
    }
    if (BN && tid < 128) {
        const float mu = stats[tid] * (1.0f / NN);
        const float var = stats[128 + tid] * (1.0f / NN) - mu * mu;
        const float a = gmv[tid] * rsqrtf(var + BN_EPS);
        abv[tid] = a;
        abv[128 + tid] = fmaf(-mu, a, bev[tid]);
    }
    __syncthreads();

    const int lane = tid & 63;
    const int ln = lane & 15, lg = lane >> 4, wv = tid >> 6;
    const int nb = blockIdx.x * 64 + wv * 16;
    const int arow = (nb + ln < NN) ? nb + ln : NN - 1;
    const int sw = (ln & 7) << 4;

    // x fragments once (BN folded here if enabled)
    half8v xf[4];
#pragma unroll
    for (int kc = 0; kc < 4; ++kc) {
        const float* ap = xin + (size_t)arow * 128 + kc * 32 + lg * 8;
        const float4 u0 = *(const float4*)(ap);
        const float4 u1 = *(const float4*)(ap + 4);
        float av[8] = {u0.x, u0.y, u0.z, u0.w, u1.x, u1.y, u1.z, u1.w};
#pragma unroll
        for (int i = 0; i < 8; ++i) {
            if (BN) {
                const int ch = kc * 32 + lg * 8 + i;
                av[i] = fmaf(av[i], abv[ch], abv[128 + ch]);
            }
            xf[kc][i] = (_Float16)av[i];
        }
    }

    const char* wg = (const char*)Wg;
#pragma unroll
    for (int pass = 0; pass < 2; ++pass) {
        if (pass == 1) {
            __syncthreads();
            const int4* src = (const int4*)(Wimg + 32768);
            int4* dst = (int4*)Wg;
            for (int j = tid; j < 4096; j += 256) dst[j] = src[j];
            __syncthreads();
        }

        f32x4 accF[8], accS[8];
        const f32x4 zz = {0.f, 0.f, 0.f, 0.f};
#pragma unroll
        for (int nt = 0; nt < 8; ++nt) { accF[nt] = zz; accS[nt] = zz; }

#pragma unroll
        for (int kc = 0; kc < 4; ++kc) {
            const int kofs = (kc * 64 + lg * 16) ^ sw;
#pragma unroll
            for (int nt = 0; nt < 8; ++nt) {
                const int row = nt * 16 + ln;
                const half8v bF = *(const half8v*)(wg + row * 256 + kofs);
                const half8v bS = *(const half8v*)(wg + 32768 + row * 256 + kofs);
                accF[nt] = __builtin_amdgcn_mfma_f32_16x16x32_f16(xf[kc], bF, accF[nt], 0, 0, 0);
                accS[nt] = __builtin_amdgcn_mfma_f32_16x16x32_f16(xf[kc], bS, accS[nt], 0, 0, 0);
            }
        }

        unsigned int* Tw = pass ? Tsw : Tdw;
#pragma unroll
        for (int nt = 0; nt < 8; ++nt) {
            const int ch = nt * 16 + ln;
            float addF = 0.f, addS = 0.f;
            if (pass == 0) { addF = bfv[ch]; addS = bsv[ch]; }
#pragma unroll
            for (int r = 0; r < 4; ++r) {
                const int node = nb + lg * 4 + r;
                if (node < NN) {
                    const __half2 p = __floats2half2_rn(accF[nt][r] + addF, accS[nt][r] + addS);
                    Tw[(size_t)node * 128 + ch] = *(const unsigned int*)&p;
                }
            }
        }
    }
}

// ===== fused edge kernel (R12 structure): wave-pair channel split, in-loop loads =====
// Wave pair (2w,2w+1) shares one edge range; h = gw&1 selects channels h*64..h*64+63.
template<int PERM>
__global__ __launch_bounds__(256, 4) void k_edge8(
    const unsigned int* __restrict__ Tdw, const unsigned int* __restrict__ Tsw,
    const unsigned short* __restrict__ Wimg,
    const int* __restrict__ seid, const int2* __restrict__ sds,
    const float* __restrict__ ea, const _Float16* __restrict__ eas,
    float* __restrict__ agg)
{
    __shared__ short Wt[16384];   // 32 KB edge-slice image
    const int tid = threadIdx.x;
    {
        const int4* src = (const int4*)Wimg;
        int4* dst = (int4*)Wt;
        for (int j = tid; j < 2048; j += 256) dst[j] = src[j];
    }
    __syncthreads();

    const int lane = tid & 63;
    const int ln = lane & 15, lg = lane >> 4;
    const int gw = blockIdx.x * 4 + (tid >> 6);
    const int h = gw & 1;                 // channel half
    const int rid = gw >> 1;              // edge-range id
    const int nrng = (gridDim.x * 4) >> 1;
    const int sw = (ln & 7) << 4;
    const int co = h * 64;                // channel offset

    const int NCH = NE / 16;
    const int lo = (int)(((long long)rid * NCH) / nrng);
    const int hi = (int)(((long long)(rid + 1) * NCH) / nrng);
    if (lo >= hi) return;
    const int wlo = lo * 16;
    const int Q = (hi - lo) * 4;       // edges per lane-group (contiguous)
    const int NT = hi - lo;

    const int abase = wlo + (ln >> 2) * Q + (ln & 3);  // A-row edge (+ t*4)
    const int gbase = wlo + lg * Q;                    // C-group edge base (+ t*4 + r)

    float pend[4];
    float2 gdc[4];
    int pdn = -1;
    bool first = true;
#pragma unroll
    for (int nt = 0; nt < 4; ++nt) { pend[nt] = 0.f; gdc[nt] = make_float2(0.f, 0.f); }

    const char* wb = (const char*)Wt;

    for (int t = 0; t < NT; ++t) {
        const int e4 = gbase + t * 4;
        const int4 p01 = *(const int4*)(sds + e4);
        const int4 p23 = *(const int4*)(sds + e4 + 2);
        const int sn[4] = {p01.x, p01.z, p23.x, p23.z};
        const int dn[4] = {p01.y, p01.w, p23.y, p23.w};

        // A fragments (full K=64 row regardless of channel half)
        half8v a0, a1;
        if (PERM) {
            const _Float16* ap = eas + (size_t)(abase + t * 4) * 64;
            a0 = *(const half8v*)(ap + lg * 8);
            a1 = *(const half8v*)(ap + 32 + lg * 8);
        } else {
            const int eln = seid[abase + t * 4];
            const float* ap = ea + (size_t)eln * 64 + lg * 8;
            const float4 v0 = *(const float4*)(ap);
            const float4 v1 = *(const float4*)(ap + 4);
            const float4 v2 = *(const float4*)(ap + 32);
            const float4 v3 = *(const float4*)(ap + 36);
            const float av0[8] = {v0.x, v0.y, v0.z, v0.w, v1.x, v1.y, v1.z, v1.w};
            const float av1[8] = {v2.x, v2.y, v2.z, v2.w, v3.x, v3.y, v3.z, v3.w};
#pragma unroll
            for (int i = 0; i < 8; ++i) { a0[i] = (_Float16)av0[i]; a1[i] = (_Float16)av1[i]; }
        }

        // Tsrc gathers for this channel half (256 B contiguous per edge)
        unsigned int gsw[4][4];
#pragma unroll
        for (int r = 0; r < 4; ++r)
#pragma unroll
            for (int nt = 0; nt < 4; ++nt)
                gsw[r][nt] = Tsw[(size_t)sn[r] * 128 + co + nt * 16 + ln];

        f32x4 accf[4], accs[4];
        const f32x4 zz = {0.f, 0.f, 0.f, 0.f};
#pragma unroll
        for (int nt = 0; nt < 4; ++nt) { accf[nt] = zz; accs[nt] = zz; }

#pragma unroll
        for (int nt = 0; nt < 4; ++nt) {
            const int rowf = co + nt * 16 + ln;
            const half8v bf0 = *(const half8v*)(wb + rowf * 128 + ((lg * 16) ^ sw));
            const half8v bf1 = *(const half8v*)(wb + rowf * 128 + ((64 + lg * 16) ^ sw));
            const half8v bs0 = *(const half8v*)(wb + (128 + rowf) * 128 + ((lg * 16) ^ sw));
            const half8v bs1 = *(const half8v*)(wb + (128 + rowf) * 128 + ((64 + lg * 16) ^ sw));
            accf[nt] = __builtin_amdgcn_mfma_f32_16x16x32_f16(a0, bf0, accf[nt], 0, 0, 0);
            accf[nt] = __builtin_amdgcn_mfma_f32_16x16x32_f16(a1, bf1, accf[nt], 0, 0, 0);
            accs[nt] = __builtin_amdgcn_mfma_f32_16x16x32_f16(a0, bs0, accs[nt], 0, 0, 0);
            accs[nt] = __builtin_amdgcn_mfma_f32_16x16x32_f16(a1, bs1, accs[nt], 0, 0, 0);
        }

        // epilogue: runs carried across tiles; interior runs = plain store
#pragma unroll
        for (int r = 0; r < 4; ++r) {
            if (dn[r] != pdn) {
                if (pdn >= 0) {
                    float* xo = agg + (size_t)pdn * 128 + co + ln;
                    if (first) {
#pragma unroll
                        for (int nt = 0; nt < 4; ++nt) atomicAdd(xo + nt * 16, pend[nt]);
                    } else {
#pragma unroll
                        for (int nt = 0; nt < 4; ++nt) xo[nt * 16] = pend[nt];
                    }
                    first = false;
                }
                pdn = dn[r];
#pragma unroll
                for (int nt = 0; nt < 4; ++nt) {
                    const __half2 hd = *(const __half2*)&Tdw[(size_t)pdn * 128 + co + nt * 16 + ln];
                    gdc[nt] = __half22float2(hd);
                    pend[nt] = 0.f;
                }
            }
#pragma unroll
            for (int nt = 0; nt < 4; ++nt) {
                const __half2 hw = *(const __half2*)&gsw[r][nt];
                const float2 gs = __half22float2(hw);
                const float F = accf[nt][r] + gdc[nt].x + gs.x;
                const float S = accs[nt][r] + gdc[nt].y + gs.y;
                pend[nt] += sigm(F) * sofp(S);
            }
        }
    }
    // final run touches the range boundary: atomic
    {
        float* xo = agg + (size_t)pdn * 128 + co + ln;
#pragma unroll
        for (int nt = 0; nt < 4; ++nt) atomicAdd(xo + nt * 16, pend[nt]);
    }
}

// ================= batchnorm stats (optionally BN-on-load of xv; optionally writes v) =================
template<int WRITE, int BN>
__global__ __launch_bounds__(256) void k_bn_stats2(
    const float* __restrict__ xv, const float* __restrict__ agg,
    const float* __restrict__ pstats, const float* __restrict__ pgm, const float* __restrict__ pbe,
    float* __restrict__ vout, float* __restrict__ stats)
{
    const int c = threadIdx.x & 127;
    const int half = threadIdx.x >> 7;
    float a = 1.0f, b = 0.0f;
    if (BN) {
        const float mu = pstats[c] * (1.0f / NN);
        const float var = pstats[128 + c] * (1.0f / NN) - mu * mu;
        a = pgm[c] * rsqrtf(var + BN_EPS);
        b = fmaf(-mu, a, pbe[c]);
    }
    float s = 0.0f, q = 0.0f;
    for (int r = blockIdx.x * 2 + half; r < NN; r += gridDim.x * 2) {
        float v = xv[(size_t)r * 128 + c];
        if (BN) v = fmaf(v, a, b);
        v += agg[(size_t)r * 128 + c];
        if (WRITE) vout[(size_t)r * 128 + c] = v;
        s += v; q = fmaf(v, v, q);
    }
    __shared__ float sh[2][128];
    if (half) { sh[0][c] = s; sh[1][c] = q; }
    __syncthreads();
    if (!half) {
        s += sh[0][c]; q += sh[1][c];
        atomicAdd(&stats[c], s);
        atomicAdd(&stats[128 + c], q);
    }
}

// final: out-pool of BN1(BN0(v1)+agg1)
__global__ __launch_bounds__(256) void k_bn_apply_pool2(
    const float* __restrict__ v1, const float* __restrict__ agg,
    const float* __restrict__ stats0, const float* __restrict__ gm0, const float* __restrict__ be0,
    const float* __restrict__ stats1, const float* __restrict__ gm1, const float* __restrict__ be1,
    const int* __restrict__ bat, float* __restrict__ pool, float* __restrict__ cnt)
{
    const int c = threadIdx.x & 127;
    const int half = threadIdx.x >> 7;
    float a0, b0, a1, b1;
    {
        const float mu = stats0[c] * (1.0f / NN);
        const float var = stats0[128 + c] * (1.0f / NN) - mu * mu;
        a0 = gm0[c] * rsqrtf(var + BN_EPS);
        b0 = fmaf(-mu, a0, be0[c]);
    }
    {
        const float mu = stats1[c] * (1.0f / NN);
        const float var = stats1[128 + c] * (1.0f / NN) - mu * mu;
        a1 = gm1[c] * rsqrtf(var + BN_EPS);
        b1 = fmaf(-mu, a1, be1[c]);
    }
    for (int r = blockIdx.x * 2 + half; r < NN; r += gridDim.x * 2) {
        const int g = bat[r];
        const float v = fmaf(v1[(size_t)r * 128 + c], a0, b0) + agg[(size_t)r * 128 + c];
        atomicAdd(&pool[(size_t)g * 128 + c], fmaf(v, a1, b1));
        if (c == 0) atomicAdd(&cnt[g], 1.0f);
    }
}

__global__ __launch_bounds__(256) void k_pool_fin(const float* __restrict__ pool, const float* __restrict__ cnt,
                                                  float* __restrict__ out)
{
    const int i = blockIdx.x * 256 + threadIdx.x;
    out[i] = pool[i] / fmaxf(cnt[i >> 7], 1.0f);
}

extern "C" void kernel_launch(void* const* d_in, const int* in_sizes, int n_in,
                              void* d_out, int out_size, void* d_ws, size_t ws_size,
                              hipStream_t stream)
{
    const float* x   = (const float*)d_in[0];
    const int*   ei  = (const int*)d_in[1];
    const float* ea  = (const float*)d_in[2];
    const int*   bat = (const int*)d_in[3];
    const float* Wf[2] = { (const float*)d_in[4],  (const float*)d_in[10] };
    const float* bf[2] = { (const float*)d_in[5],  (const float*)d_in[11] };
    const float* Ws[2] = { (const float*)d_in[6],  (const float*)d_in[12] };
    const float* bs[2] = { (const float*)d_in[7],  (const float*)d_in[13] };
    const float* gm[2] = { (const float*)d_in[8],  (const float*)d_in[14] };
    const float* be[2] = { (const float*)d_in[9],  (const float*)d_in[15] };

    char* wsp = (char*)d_ws;
    unsigned int* Tdw = (unsigned int*)wsp;                 // [N][128] packed half2 (f,s)
    unsigned int* Tsw = Tdw + (size_t)NN * 128;             // [N][128] packed half2
    float* agg    = (float*)(Tsw + (size_t)NN * 128);       // [N][128] fp32
    float* xb1    = agg + (size_t)NN * 128;                 // [N][128] fp32: v1 = x + agg0 (pre-BN)
    float* stats0 = xb1 + (size_t)NN * 128;                 // 256
    float* stats1 = stats0 + 256;                           // 256
    float* pool   = stats1 + 256;                           // [G][128]
    float* cnt    = pool + (size_t)NG * 128;                // G
    int* hist    = (int*)(cnt + NG);                        // NNP
    int* partial = hist + NNP;                              // 256
    int* topoff  = partial + 256;                           // 256
    int* cursor  = topoff + 256;                            // NN
    int* seid    = cursor + NN;                             // NE
    int* epos    = seid + NE;                               // NE
    int2* sds    = (int2*)(epos + NE);                      // NE int2
    unsigned short* Wn16 = (unsigned short*)(sds + NE);     // 131072 ushorts
    unsigned short* We16 = Wn16 + 131072;                   // 32768 ushorts
    _Float16* eas = (_Float16*)(We16 + 32768);              // NE*64 halves (102.4 MB)

    const size_t need = (size_t)((char*)(eas + (size_t)NE * 64) - (char*)d_ws);
    const bool perm = ws_size >= need;

    hipMemsetAsync(pool, 0, ((size_t)NG * 128 + NG) * sizeof(float), stream);
    hipMemsetAsync(hist, 0, NNP * sizeof(int), stream);
    hipMemsetAsync(stats0, 0, 512 * sizeof(float), stream);

    // one-time: W conversion + dst-sorted edge permutation (+ ea perm/cvt)
    k_wcvt<<<640, 256, 0, stream>>>(Wf[0], Ws[0], Wf[1], Ws[1], Wn16, We16);
    k_hist<<<(NE + 255) / 256, 256, 0, stream>>>(ei, hist);
    k_scan_partial<<<196, 256, 0, stream>>>(hist, partial);
    k_scan_top<<<1, 256, 0, stream>>>(partial, topoff);
    k_scan_final<<<196, 256, 0, stream>>>(hist, topoff, cursor);
    k_scatter<<<(NE + 255) / 256, 256, 0, stream>>>(ei, cursor, seid, epos, sds);
    if (perm) k_eperm2<<<NE / 16, 256, 0, stream>>>(epos, ea, eas);

    // ---- layer 1 ----
    k_nl2<0><<<782, 256, 0, stream>>>(x, Wn16, bf[0], bs[0], nullptr, nullptr, nullptr, Tdw, Tsw);
    hipMemsetAsync(agg, 0, (size_t)NN * 128 * sizeof(float), stream);
    if (perm) k_edge8<1><<<1024, 256, 0, stream>>>(Tdw, Tsw, We16, seid, sds, ea, eas, agg);
    else      k_edge8<0><<<1024, 256, 0, stream>>>(Tdw, Tsw, We16, seid, sds, ea, eas, agg);
    // stats0 over v1 = x + agg0; also materialize v1 into xb1
    k_bn_stats2<1, 0><<<256, 256, 0, stream>>>(x, agg, nullptr, nullptr, nullptr, xb1, stats0);

    // ---- layer 2 ----  (BN0 folded into consumers)
    k_nl2<1><<<782, 256, 0, stream>>>(xb1, Wn16 + 65536, bf[1], bs[1], stats0, gm[0], be[0], Tdw, Tsw);
    hipMemsetAsync(agg, 0, (size_t)NN * 128 * sizeof(float), stream);
    hipMemsetAsync(stats1, 0, 256 * sizeof(float), stream);
    if (perm) k_edge8<1><<<1024, 256, 0, stream>>>(Tdw, Tsw, We16 + 16384, seid, sds, ea, eas, agg);
    else      k_edge8<0><<<1024, 256, 0, stream>>>(Tdw, Tsw, We16 + 16384, seid, sds, ea, eas, agg);
    k_bn_stats2<0, 1><<<256, 256, 0, stream>>>(xb1, agg, stats0, gm[0], be[0], nullptr, stats1);
    k_bn_apply_pool2<<<256, 256, 0, stream>>>(xb1, agg, stats0, gm[0], be[0], stats1, gm[1], be[1], bat, pool, cnt);

    k_pool_fin<<<NG * 128 / 256, 256, 0, stream>>>(pool, cnt, (float*)d_out);
}

// Round 15
// 928.379 us; speedup vs baseline: 1.1018x; 1.0444x over previous
//
#include <hip/hip_runtime.h>
#include <hip/hip_fp16.h>

#define NN 50000
#define NE 800000
#define NG 256
#define BN_EPS 1e-5f
#define NNP (196 * 256)   // padded bins for scan

typedef __attribute__((ext_vector_type(8))) _Float16 half8v;
typedef __attribute__((ext_vector_type(4))) _Float16 half4v;
typedef __attribute__((ext_vector_type(4))) float f32x4;

__device__ __forceinline__ float sigm(float x) { return 1.0f / (1.0f + __expf(-x)); }
__device__ __forceinline__ float sofp(float x) { return fmaxf(x, 0.0f) + __logf(1.0f + __expf(-fabsf(x))); }

// ================= CSR build (counting sort by dst) =================
__global__ __launch_bounds__(256) void k_hist(const int* __restrict__ ei, int* __restrict__ hist)
{
    const int e = blockIdx.x * 256 + threadIdx.x;
    if (e < NE) atomicAdd(&hist[ei[NE + e]], 1);
}

__global__ __launch_bounds__(256) void k_scan_partial(const int* __restrict__ hist, int* __restrict__ partial)
{
    __shared__ int s[256];
    const int t = threadIdx.x;
    s[t] = hist[blockIdx.x * 256 + t];
    __syncthreads();
    for (int off = 1; off < 256; off <<= 1) {
        const int u = (t >= off) ? s[t - off] : 0;
        __syncthreads();
        s[t] += u;
        __syncthreads();
    }
    if (t == 255) partial[blockIdx.x] = s[255];
}

__global__ __launch_bounds__(256) void k_scan_top(const int* __restrict__ partial, int* __restrict__ topoff)
{
    __shared__ int s[256];
    const int t = threadIdx.x;
    const int v = (t < 196) ? partial[t] : 0;
    s[t] = v;
    __syncthreads();
    for (int off = 1; off < 256; off <<= 1) {
        const int u = (t >= off) ? s[t - off] : 0;
        __syncthreads();
        s[t] += u;
        __syncthreads();
    }
    if (t < 196) topoff[t] = s[t] - v;  // exclusive
}

__global__ __launch_bounds__(256) void k_scan_final(const int* __restrict__ hist, const int* __restrict__ topoff,
                                                    int* __restrict__ cursor)
{
    __shared__ int s[256];
    const int t = threadIdx.x;
    const int i = blockIdx.x * 256 + t;
    const int v = hist[i];
    s[t] = v;
    __syncthreads();
    for (int off = 1; off < 256; off <<= 1) {
        const int u = (t >= off) ? s[t - off] : 0;
        __syncthreads();
        s[t] += u;
        __syncthreads();
    }
    if (i < NN) cursor[i] = topoff[blockIdx.x] + s[t] - v;  // exclusive prefix
}

__global__ __launch_bounds__(256) void k_scatter(const int* __restrict__ ei, int* __restrict__ cursor,
                                                 int* __restrict__ seid, int* __restrict__ epos,
                                                 int2* __restrict__ sds)
{
    const int e = blockIdx.x * 256 + threadIdx.x;
    if (e < NE) {
        const int d = ei[NE + e];
        const int pos = atomicAdd(&cursor[d], 1);
        seid[pos] = e;
        epos[e] = pos;
        sds[pos] = make_int2(ei[e], d);
    }
}

// permute edge_attr into sorted order, fp16: SEQUENTIAL read, scattered 128B write
__global__ __launch_bounds__(256) void k_eperm2(const int* __restrict__ epos, const float* __restrict__ ea,
                                                _Float16* __restrict__ eas)
{
    const int e = blockIdx.x * 16 + (threadIdx.x >> 4);
    const int j = threadIdx.x & 15;
    const int p = epos[e];
    const float4 v = *(const float4*)(ea + (size_t)e * 64 + j * 4);
    half4v h;
    h[0] = (_Float16)v.x; h[1] = (_Float16)v.y; h[2] = (_Float16)v.z; h[3] = (_Float16)v.w;
    *(half4v*)(eas + (size_t)p * 64 + j * 4) = h;
}

// ================= one-time W conversion to fp16 pre-swizzled images =================
__global__ __launch_bounds__(256) void k_wcvt(
    const float* __restrict__ Wf0, const float* __restrict__ Ws0,
    const float* __restrict__ Wf1, const float* __restrict__ Ws1,
    unsigned short* __restrict__ Wn16, unsigned short* __restrict__ We16)
{
    const int i = blockIdx.x * 256 + threadIdx.x;
    if (i >= 2 * 81920) return;
    const int l = i / 81920;
    int r = i % 81920;
    const float* Wf = l ? Wf1 : Wf0;
    const float* Ws = l ? Ws1 : Ws0;
    if (r < 65536) {
        const int s = r >> 14;          // 0..3
        const int t = s & 1, g = s >> 1;
        const int j = r & 16383;
        const int k = j >> 7, ch = j & 127;
        const float v = (g ? Ws : Wf)[(size_t)(t * 128 + k) * 128 + ch];
        unsigned short* img = Wn16 + (size_t)(l * 2 + t) * 32768;
        const int boff = g * 32768 + ch * 256 + ((k * 2) ^ ((ch & 7) << 4));
        *(unsigned short*)((char*)img + boff) = __half_as_ushort(__float2half(v));
    } else {
        r -= 65536;
        const int g = r >> 13;
        const int j = r & 8191;
        const int k = j >> 7, ch = j & 127;
        const float v = (g ? Ws : Wf)[(size_t)(256 + k) * 128 + ch];
        const int row = g * 128 + ch;
        unsigned short* img = We16 + (size_t)l * 16384;
        const int boff = row * 128 + ((k * 2) ^ ((row & 7) << 4));
        *(unsigned short*)((char*)img + boff) = __half_as_ushort(__float2half(v));
    }
}

// ===== node linear, gate-split staging: 32 KB LDS -> 4 blocks/CU =====
// pass t: 0 -> Tdw (+bias), 1 -> Tsw. Per pass: stage f-gate image, accF; stage s-gate, accS.
// BN=1: fold BN(stats,gm,be) into the x load (x fragments held in regs across all passes).
template<int BN>
__global__ __launch_bounds__(256) void k_nl3(
    const float* __restrict__ xin, const unsigned short* __restrict__ Wimg,
    const float* __restrict__ bfv, const float* __restrict__ bsv,
    const float* __restrict__ stats, const float* __restrict__ gmv, const float* __restrict__ bev,
    unsigned int* __restrict__ Tdw, unsigned int* __restrict__ Tsw)
{
    __shared__ short Wg[16384];   // 32 KB: one gate image at a time
    __shared__ float abv[256];
    const int tid = threadIdx.x;
    if (BN && tid < 128) {
        const float mu = stats[tid] * (1.0f / NN);
        const float var = stats[128 + tid] * (1.0f / NN) - mu * mu;
        const float a = gmv[tid] * rsqrtf(var + BN_EPS);
        abv[tid] = a;
        abv[128 + tid] = fmaf(-mu, a, bev[tid]);
    }
    if (BN) __syncthreads();

    const int lane = tid & 63;
    const int ln = lane & 15, lg = lane >> 4, wv = tid >> 6;
    const int nb = blockIdx.x * 64 + wv * 16;
    const int arow = (nb + ln < NN) ? nb + ln : NN - 1;
    const int sw = (ln & 7) << 4;

    // x fragments once (BN folded here if enabled)
    half8v xf[4];
#pragma unroll
    for (int kc = 0; kc < 4; ++kc) {
        const float* ap = xin + (size_t)arow * 128 + kc * 32 + lg * 8;
        const float4 u0 = *(const float4*)(ap);
        const float4 u1 = *(const float4*)(ap + 4);
        float av[8] = {u0.x, u0.y, u0.z, u0.w, u1.x, u1.y, u1.z, u1.w};
#pragma unroll
        for (int i = 0; i < 8; ++i) {
            if (BN) {
                const int ch = kc * 32 + lg * 8 + i;
                av[i] = fmaf(av[i], abv[ch], abv[128 + ch]);
            }
            xf[kc][i] = (_Float16)av[i];
        }
    }

    const char* wg = (const char*)Wg;
#pragma unroll
    for (int pass = 0; pass < 2; ++pass) {
        f32x4 accF[8], accS[8];
        const f32x4 zz = {0.f, 0.f, 0.f, 0.f};
#pragma unroll
        for (int nt = 0; nt < 8; ++nt) { accF[nt] = zz; accS[nt] = zz; }

#pragma unroll
        for (int g = 0; g < 2; ++g) {
            __syncthreads();   // previous image reads done
            {
                const int4* src = (const int4*)(Wimg + pass * 32768 + g * 16384);
                int4* dst = (int4*)Wg;
                for (int j = tid; j < 2048; j += 256) dst[j] = src[j];
            }
            __syncthreads();
#pragma unroll
            for (int kc = 0; kc < 4; ++kc) {
                const int kofs = (kc * 64 + lg * 16) ^ sw;
#pragma unroll
                for (int nt = 0; nt < 8; ++nt) {
                    const half8v b = *(const half8v*)(wg + (nt * 16 + ln) * 256 + kofs);
                    if (g == 0) accF[nt] = __builtin_amdgcn_mfma_f32_16x16x32_f16(xf[kc], b, accF[nt], 0, 0, 0);
                    else        accS[nt] = __builtin_amdgcn_mfma_f32_16x16x32_f16(xf[kc], b, accS[nt], 0, 0, 0);
                }
            }
        }

        unsigned int* Tw = pass ? Tsw : Tdw;
#pragma unroll
        for (int nt = 0; nt < 8; ++nt) {
            const int ch = nt * 16 + ln;
            float addF = 0.f, addS = 0.f;
            if (pass == 0) { addF = bfv[ch]; addS = bsv[ch]; }
#pragma unroll
            for (int r = 0; r < 4; ++r) {
                const int node = nb + lg * 4 + r;
                if (node < NN) {
                    const __half2 p = __floats2half2_rn(accF[nt][r] + addF, accS[nt][r] + addS);
                    Tw[(size_t)node * 128 + ch] = *(const unsigned int*)&p;
                }
            }
        }
    }
}

// ===== fused edge kernel (R12 structure): wave-pair channel split, in-loop loads =====
// Wave pair (2w,2w+1) shares one edge range; h = gw&1 selects channels h*64..h*64+63.
template<int PERM>
__global__ __launch_bounds__(256, 4) void k_edge8(
    const unsigned int* __restrict__ Tdw, const unsigned int* __restrict__ Tsw,
    const unsigned short* __restrict__ Wimg,
    const int* __restrict__ seid, const int2* __restrict__ sds,
    const float* __restrict__ ea, const _Float16* __restrict__ eas,
    float* __restrict__ agg)
{
    __shared__ short Wt[16384];   // 32 KB edge-slice image
    const int tid = threadIdx.x;
    {
        const int4* src = (const int4*)Wimg;
        int4* dst = (int4*)Wt;
        for (int j = tid; j < 2048; j += 256) dst[j] = src[j];
    }
    __syncthreads();

    const int lane = tid & 63;
    const int ln = lane & 15, lg = lane >> 4;
    const int gw = blockIdx.x * 4 + (tid >> 6);
    const int h = gw & 1;                 // channel half
    const int rid = gw >> 1;              // edge-range id
    const int nrng = (gridDim.x * 4) >> 1;
    const int sw = (ln & 7) << 4;
    const int co = h * 64;                // channel offset

    const int NCH = NE / 16;
    const int lo = (int)(((long long)rid * NCH) / nrng);
    const int hi = (int)(((long long)(rid + 1) * NCH) / nrng);
    if (lo >= hi) return;
    const int wlo = lo * 16;
    const int Q = (hi - lo) * 4;       // edges per lane-group (contiguous)
    const int NT = hi - lo;

    const int abase = wlo + (ln >> 2) * Q + (ln & 3);  // A-row edge (+ t*4)
    const int gbase = wlo + lg * Q;                    // C-group edge base (+ t*4 + r)

    float pend[4];
    float2 gdc[4];
    int pdn = -1;
    bool first = true;
#pragma unroll
    for (int nt = 0; nt < 4; ++nt) { pend[nt] = 0.f; gdc[nt] = make_float2(0.f, 0.f); }

    const char* wb = (const char*)Wt;

    for (int t = 0; t < NT; ++t) {
        const int e4 = gbase + t * 4;
        const int4 p01 = *(const int4*)(sds + e4);
        const int4 p23 = *(const int4*)(sds + e4 + 2);
        const int sn[4] = {p01.x, p01.z, p23.x, p23.z};
        const int dn[4] = {p01.y, p01.w, p23.y, p23.w};

        // A fragments (full K=64 row regardless of channel half)
        half8v a0, a1;
        if (PERM) {
            const _Float16* ap = eas + (size_t)(abase + t * 4) * 64;
            a0 = *(const half8v*)(ap + lg * 8);
            a1 = *(const half8v*)(ap + 32 + lg * 8);
        } else {
            const int eln = seid[abase + t * 4];
            const float* ap = ea + (size_t)eln * 64 + lg * 8;
            const float4 v0 = *(const float4*)(ap);
            const float4 v1 = *(const float4*)(ap + 4);
            const float4 v2 = *(const float4*)(ap + 32);
            const float4 v3 = *(const float4*)(ap + 36);
            const float av0[8] = {v0.x, v0.y, v0.z, v0.w, v1.x, v1.y, v1.z, v1.w};
            const float av1[8] = {v2.x, v2.y, v2.z, v2.w, v3.x, v3.y, v3.z, v3.w};
#pragma unroll
            for (int i = 0; i < 8; ++i) { a0[i] = (_Float16)av0[i]; a1[i] = (_Float16)av1[i]; }
        }

        // Tsrc gathers for this channel half (256 B contiguous per edge)
        unsigned int gsw[4][4];
#pragma unroll
        for (int r = 0; r < 4; ++r)
#pragma unroll
            for (int nt = 0; nt < 4; ++nt)
                gsw[r][nt] = Tsw[(size_t)sn[r] * 128 + co + nt * 16 + ln];

        f32x4 accf[4], accs[4];
        const f32x4 zz = {0.f, 0.f, 0.f, 0.f};
#pragma unroll
        for (int nt = 0; nt < 4; ++nt) { accf[nt] = zz; accs[nt] = zz; }

#pragma unroll
        for (int nt = 0; nt < 4; ++nt) {
            const int rowf = co + nt * 16 + ln;
            const half8v bf0 = *(const half8v*)(wb + rowf * 128 + ((lg * 16) ^ sw));
            const half8v bf1 = *(const half8v*)(wb + rowf * 128 + ((64 + lg * 16) ^ sw));
            const half8v bs0 = *(const half8v*)(wb + (128 + rowf) * 128 + ((lg * 16) ^ sw));
            const half8v bs1 = *(const half8v*)(wb + (128 + rowf) * 128 + ((64 + lg * 16) ^ sw));
            accf[nt] = __builtin_amdgcn_mfma_f32_16x16x32_f16(a0, bf0, accf[nt], 0, 0, 0);
            accf[nt] = __builtin_amdgcn_mfma_f32_16x16x32_f16(a1, bf1, accf[nt], 0, 0, 0);
            accs[nt] = __builtin_amdgcn_mfma_f32_16x16x32_f16(a0, bs0, accs[nt], 0, 0, 0);
            accs[nt] = __builtin_amdgcn_mfma_f32_16x16x32_f16(a1, bs1, accs[nt], 0, 0, 0);
        }

        // epilogue: runs carried across tiles; interior runs = plain store
#pragma unroll
        for (int r = 0; r < 4; ++r) {
            if (dn[r] != pdn) {
                if (pdn >= 0) {
                    float* xo = agg + (size_t)pdn * 128 + co + ln;
                    if (first) {
#pragma unroll
                        for (int nt = 0; nt < 4; ++nt) atomicAdd(xo + nt * 16, pend[nt]);
                    } else {
#pragma unroll
                        for (int nt = 0; nt < 4; ++nt) xo[nt * 16] = pend[nt];
                    }
                    first = false;
                }
                pdn = dn[r];
#pragma unroll
                for (int nt = 0; nt < 4; ++nt) {
                    const __half2 hd = *(const __half2*)&Tdw[(size_t)pdn * 128 + co + nt * 16 + ln];
                    gdc[nt] = __half22float2(hd);
                    pend[nt] = 0.f;
                }
            }
#pragma unroll
            for (int nt = 0; nt < 4; ++nt) {
                const __half2 hw = *(const __half2*)&gsw[r][nt];
                const float2 gs = __half22float2(hw);
                const float F = accf[nt][r] + gdc[nt].x + gs.x;
                const float S = accs[nt][r] + gdc[nt].y + gs.y;
                pend[nt] += sigm(F) * sofp(S);
            }
        }
    }
    // final run touches the range boundary: atomic
    {
        float* xo = agg + (size_t)pdn * 128 + co + ln;
#pragma unroll
        for (int nt = 0; nt < 4; ++nt) atomicAdd(xo + nt * 16, pend[nt]);
    }
}

// ================= batchnorm stats (optionally BN-on-load of xv; optionally writes v) =================
template<int WRITE, int BN>
__global__ __launch_bounds__(256) void k_bn_stats2(
    const float* __restrict__ xv, const float* __restrict__ agg,
    const float* __restrict__ pstats, const float* __restrict__ pgm, const float* __restrict__ pbe,
    float* __restrict__ vout, float* __restrict__ stats)
{
    const int c = threadIdx.x & 127;
    const int half = threadIdx.x >> 7;
    float a = 1.0f, b = 0.0f;
    if (BN) {
        const float mu = pstats[c] * (1.0f / NN);
        const float var = pstats[128 + c] * (1.0f / NN) - mu * mu;
        a = pgm[c] * rsqrtf(var + BN_EPS);
        b = fmaf(-mu, a, pbe[c]);
    }
    float s = 0.0f, q = 0.0f;
    for (int r = blockIdx.x * 2 + half; r < NN; r += gridDim.x * 2) {
        float v = xv[(size_t)r * 128 + c];
        if (BN) v = fmaf(v, a, b);
        v += agg[(size_t)r * 128 + c];
        if (WRITE) vout[(size_t)r * 128 + c] = v;
        s += v; q = fmaf(v, v, q);
    }
    __shared__ float sh[2][128];
    if (half) { sh[0][c] = s; sh[1][c] = q; }
    __syncthreads();
    if (!half) {
        s += sh[0][c]; q += sh[1][c];
        atomicAdd(&stats[c], s);
        atomicAdd(&stats[128 + c], q);
    }
}

// final: out-pool of BN1(BN0(v1)+agg1)
__global__ __launch_bounds__(256) void k_bn_apply_pool2(
    const float* __restrict__ v1, const float* __restrict__ agg,
    const float* __restrict__ stats0, const float* __restrict__ gm0, const float* __restrict__ be0,
    const float* __restrict__ stats1, const float* __restrict__ gm1, const float* __restrict__ be1,
    const int* __restrict__ bat, float* __restrict__ pool, float* __restrict__ cnt)
{
    const int c = threadIdx.x & 127;
    const int half = threadIdx.x >> 7;
    float a0, b0, a1, b1;
    {
        const float mu = stats0[c] * (1.0f / NN);
        const float var = stats0[128 + c] * (1.0f / NN) - mu * mu;
        a0 = gm0[c] * rsqrtf(var + BN_EPS);
        b0 = fmaf(-mu, a0, be0[c]);
    }
    {
        const float mu = stats1[c] * (1.0f / NN);
        const float var = stats1[128 + c] * (1.0f / NN) - mu * mu;
        a1 = gm1[c] * rsqrtf(var + BN_EPS);
        b1 = fmaf(-mu, a1, be1[c]);
    }
    for (int r = blockIdx.x * 2 + half; r < NN; r += gridDim.x * 2) {
        const int g = bat[r];
        const float v = fmaf(v1[(size_t)r * 128 + c], a0, b0) + agg[(size_t)r * 128 + c];
        atomicAdd(&pool[(size_t)g * 128 + c], fmaf(v, a1, b1));
        if (c == 0) atomicAdd(&cnt[g], 1.0f);
    }
}

__global__ __launch_bounds__(256) void k_pool_fin(const float* __restrict__ pool, const float* __restrict__ cnt,
                                                  float* __restrict__ out)
{
    const int i = blockIdx.x * 256 + threadIdx.x;
    out[i] = pool[i] / fmaxf(cnt[i >> 7], 1.0f);
}

extern "C" void kernel_launch(void* const* d_in, const int* in_sizes, int n_in,
                              void* d_out, int out_size, void* d_ws, size_t ws_size,
                              hipStream_t stream)
{
    const float* x   = (const float*)d_in[0];
    const int*   ei  = (const int*)d_in[1];
    const float* ea  = (const float*)d_in[2];
    const int*   bat = (const int*)d_in[3];
    const float* Wf[2] = { (const float*)d_in[4],  (const float*)d_in[10] };
    const float* bf[2] = { (const float*)d_in[5],  (const float*)d_in[11] };
    const float* Ws[2] = { (const float*)d_in[6],  (const float*)d_in[12] };
    const float* bs[2] = { (const float*)d_in[7],  (const float*)d_in[13] };
    const float* gm[2] = { (const float*)d_in[8],  (const float*)d_in[14] };
    const float* be[2] = { (const float*)d_in[9],  (const float*)d_in[15] };

    char* wsp = (char*)d_ws;
    unsigned int* Tdw = (unsigned int*)wsp;                 // [N][128] packed half2 (f,s)
    unsigned int* Tsw = Tdw + (size_t)NN * 128;             // [N][128] packed half2
    float* agg    = (float*)(Tsw + (size_t)NN * 128);       // [N][128] fp32
    float* xb1    = agg + (size_t)NN * 128;                 // [N][128] fp32: v1 = x + agg0 (pre-BN)
    float* stats0 = xb1 + (size_t)NN * 128;                 // 256
    float* stats1 = stats0 + 256;                           // 256
    float* pool   = stats1 + 256;                           // [G][128]
    float* cnt    = pool + (size_t)NG * 128;                // G
    int* hist    = (int*)(cnt + NG);                        // NNP
    int* partial = hist + NNP;                              // 256
    int* topoff  = partial + 256;                           // 256
    int* cursor  = topoff + 256;                            // NN
    int* seid    = cursor + NN;                             // NE
    int* epos    = seid + NE;                               // NE
    int2* sds    = (int2*)(epos + NE);                      // NE int2
    unsigned short* Wn16 = (unsigned short*)(sds + NE);     // 131072 ushorts
    unsigned short* We16 = Wn16 + 131072;                   // 32768 ushorts
    _Float16* eas = (_Float16*)(We16 + 32768);              // NE*64 halves (102.4 MB)

    const size_t need = (size_t)((char*)(eas + (size_t)NE * 64) - (char*)d_ws);
    const bool perm = ws_size >= need;

    hipMemsetAsync(pool, 0, ((size_t)NG * 128 + NG) * sizeof(float), stream);
    hipMemsetAsync(hist, 0, NNP * sizeof(int), stream);
    hipMemsetAsync(stats0, 0, 512 * sizeof(float), stream);

    // one-time: W conversion + dst-sorted edge permutation (+ ea perm/cvt)
    k_wcvt<<<640, 256, 0, stream>>>(Wf[0], Ws[0], Wf[1], Ws[1], Wn16, We16);
    k_hist<<<(NE + 255) / 256, 256, 0, stream>>>(ei, hist);
    k_scan_partial<<<196, 256, 0, stream>>>(hist, partial);
    k_scan_top<<<1, 256, 0, stream>>>(partial, topoff);
    k_scan_final<<<196, 256, 0, stream>>>(hist, topoff, cursor);
    k_scatter<<<(NE + 255) / 256, 256, 0, stream>>>(ei, cursor, seid, epos, sds);
    if (perm) k_eperm2<<<NE / 16, 256, 0, stream>>>(epos, ea, eas);

    // ---- layer 1 ----
    k_nl3<0><<<782, 256, 0, stream>>>(x, Wn16, bf[0], bs[0], nullptr, nullptr, nullptr, Tdw, Tsw);
    hipMemsetAsync(agg, 0, (size_t)NN * 128 * sizeof(float), stream);
    if (perm) k_edge8<1><<<1024, 256, 0, stream>>>(Tdw, Tsw, We16, seid, sds, ea, eas, agg);
    else      k_edge8<0><<<1024, 256, 0, stream>>>(Tdw, Tsw, We16, seid, sds, ea, eas, agg);
    // stats0 over v1 = x + agg0; also materialize v1 into xb1
    k_bn_stats2<1, 0><<<256, 256, 0, stream>>>(x, agg, nullptr, nullptr, nullptr, xb1, stats0);

    // ---- layer 2 ----  (BN0 folded into consumers)
    k_nl3<1><<<782, 256, 0, stream>>>(xb1, Wn16 + 65536, bf[1], bs[1], stats0, gm[0], be[0], Tdw, Tsw);
    hipMemsetAsync(agg, 0, (size_t)NN * 128 * sizeof(float), stream);
    hipMemsetAsync(stats1, 0, 256 * sizeof(float), stream);
    if (perm) k_edge8<1><<<1024, 256, 0, stream>>>(Tdw, Tsw, We16 + 16384, seid, sds, ea, eas, agg);
    else      k_edge8<0><<<1024, 256, 0, stream>>>(Tdw, Tsw, We16 + 16384, seid, sds, ea, eas, agg);
    k_bn_stats2<0, 1><<<256, 256, 0, stream>>>(xb1, agg, stats0, gm[0], be[0], nullptr, stats1);
    k_bn_apply_pool2<<<256, 256, 0, stream>>>(xb1, agg, stats0, gm[0], be[0], stats1, gm[1], be[1], bat, pool, cnt);

    k_pool_fin<<<NG * 128 / 256, 256, 0, stream>>>(pool, cnt, (float*)d_out);
}